// Round 3
// baseline (11275.432 us; speedup 1.0000x reference)
//
#include <hip/hip_runtime.h>
#include <hip/hip_cooperative_groups.h>
#include <math.h>

namespace cg = cooperative_groups;

#define B 32
#define S 41
#define T 41
#define H 1024
#define V 16384
#define BH (B*H)

__device__ __forceinline__ float fast_sigmoid(float x){ return 1.f/(1.f + __expf(-x)); }
__device__ __forceinline__ float fast_tanh(float x){
  float e = __expf(-2.f*fabsf(x));
  float r = (1.f - e)/(1.f + e);
  return copysignf(r, x);
}

// ---------------- init: h = encoder_hidden[0], c = 0 ----------------
__global__ __launch_bounds__(256) void k_init(const float* __restrict__ eh,
                                              float* __restrict__ h, float* __restrict__ c){
  int i = blockIdx.x*256 + threadIdx.x;
  h[i] = eh[i]; c[i] = 0.f;
}

// ---------------- bsum = bih + bhh ----------------
__global__ __launch_bounds__(256) void k_bsum(const float* __restrict__ a,
                                              const float* __restrict__ b, float* __restrict__ o){
  int i = blockIdx.x*256 + threadIdx.x;
  o[i] = a[i] + b[i];
}

// ---------------- gather teacher-forced embeddings: Xall[t*B+b][:] = emb[tok(t,b)] ----------------
__global__ __launch_bounds__(256) void k_gather(const float* __restrict__ emb,
    const int* __restrict__ tgt, float* __restrict__ Xall){
  int r = blockIdx.x;            // 0..T*B-1
  int t = r / B, b = r % B;
  int tok = (t==0) ? 0 : tgt[b*T + (t-1)];
  const float4* src = (const float4*)(emb + (size_t)tok*H);
  float4* dst = (float4*)(Xall + (size_t)r*H);
  dst[threadIdx.x] = src[threadIdx.x];
}

// ---------------- generic f32 GEMM: C[m][n] = sum_k A[m][k]*W[n*wstride+woff+k] + bias[n] ----------------
__global__ __launch_bounds__(256) void k_gemm(const float* __restrict__ A,
    const float* __restrict__ W, const float* __restrict__ bias,
    float* __restrict__ C, int M, int N, int K, int wstride, int woff)
{
  __shared__ float As[16][128];
  __shared__ float Ws[16][128];
  const int m0 = blockIdx.x*128, n0 = blockIdx.y*128;
  const int tid = threadIdx.x;
  const int r = tid & 127, kq = tid >> 7;
  const int tm = (tid >> 4)*8, tn = (tid & 15)*8;
  float acc[8][8] = {};
  const float* a_base = A + (size_t)(m0 + r)*K;
  const float* w_base = W + (size_t)(n0 + r)*wstride + woff;
  const bool arow_ok = (m0 + r) < M;
  for (int k0 = 0; k0 < K; k0 += 16) {
    float4 av0 = {0,0,0,0}, av1 = {0,0,0,0};
    if (arow_ok) {
      av0 = *(const float4*)(a_base + k0 + kq*4);
      av1 = *(const float4*)(a_base + k0 + 8 + kq*4);
    }
    float4 wv0 = *(const float4*)(w_base + k0 + kq*4);
    float4 wv1 = *(const float4*)(w_base + k0 + 8 + kq*4);
    __syncthreads();
    {
      int kk = kq*4;
      As[kk+0][r]=av0.x; As[kk+1][r]=av0.y; As[kk+2][r]=av0.z; As[kk+3][r]=av0.w;
      As[kk+8][r]=av1.x; As[kk+9][r]=av1.y; As[kk+10][r]=av1.z; As[kk+11][r]=av1.w;
      Ws[kk+0][r]=wv0.x; Ws[kk+1][r]=wv0.y; Ws[kk+2][r]=wv0.z; Ws[kk+3][r]=wv0.w;
      Ws[kk+8][r]=wv1.x; Ws[kk+9][r]=wv1.y; Ws[kk+10][r]=wv1.z; Ws[kk+11][r]=wv1.w;
    }
    __syncthreads();
    #pragma unroll
    for (int k=0;k<16;k++){
      float a[8], w[8];
      *(float4*)&a[0] = *(const float4*)&As[k][tm];
      *(float4*)&a[4] = *(const float4*)&As[k][tm+4];
      *(float4*)&w[0] = *(const float4*)&Ws[k][tn];
      *(float4*)&w[4] = *(const float4*)&Ws[k][tn+4];
      #pragma unroll
      for (int i=0;i<8;i++)
        #pragma unroll
        for (int j=0;j<8;j++)
          acc[i][j] = fmaf(a[i], w[j], acc[i][j]);
    }
  }
  #pragma unroll
  for (int i=0;i<8;i++){
    int m = m0 + tm + i;
    if (m >= M) break;
    float* crow = C + (size_t)m*N + n0 + tn;
    #pragma unroll
    for (int j=0;j<8;j++) crow[j] = acc[i][j] + (bias ? bias[n0 + tn + j] : 0.f);
  }
}

// ---------------- persistent cooperative kernel: the whole 41-step recurrence ----------------
// grid 256 x 512. Per step: P1 [q|gh]=h@[Wq;Whh]^T ; P2 scores+softmax ; P3 gates+LSTM.
__global__ __launch_bounds__(512) void k_loop(
    const float* __restrict__ Wq, const float* __restrict__ bq, const float* __restrict__ Whh,
    const float* __restrict__ keys, const float* __restrict__ Vw, const float* __restrict__ bV,
    const float* __restrict__ Gx, const float* __restrict__ encW,
    float* __restrict__ q, float* __restrict__ gh, float* __restrict__ w_glob,
    float* __restrict__ hcur, float* __restrict__ ccur,
    float* __restrict__ hhist, float* __restrict__ attn_out)
{
  cg::grid_group grid = cg::this_grid();
  const int tid = threadIdx.x;
  const int bid = blockIdx.x;
  __shared__ float sc_sh[64];
  __shared__ float gacc[4][128];

  for (int t = 0; t < T; ++t) {
    // ---- P1: [q | gh] = hcur @ [Wq ; Whh]^T  (5120 rows x 32 b = 163840 dots) ----
    #pragma unroll
    for (int pass = 0; pass < 2; ++pass) {
      int tk = bid*512 + tid + pass*131072;
      if (tk < 5120*32) {
        int n = tk >> 5, b = tk & 31;
        const float4* a4 = (const float4*)(hcur + b*H);
        const float4* w4 = (const float4*)((n < H) ? (Wq + (size_t)n*H)
                                                   : (Whh + (size_t)(n-H)*H));
        float4 acc0 = {0,0,0,0}, acc1 = {0,0,0,0};
        #pragma unroll 4
        for (int k = 0; k < H/4; k += 2) {
          float4 a0 = a4[k],   w0 = w4[k];
          float4 a1 = a4[k+1], w1 = w4[k+1];
          acc0.x = fmaf(a0.x,w0.x,acc0.x); acc0.y = fmaf(a0.y,w0.y,acc0.y);
          acc0.z = fmaf(a0.z,w0.z,acc0.z); acc0.w = fmaf(a0.w,w0.w,acc0.w);
          acc1.x = fmaf(a1.x,w1.x,acc1.x); acc1.y = fmaf(a1.y,w1.y,acc1.y);
          acc1.z = fmaf(a1.z,w1.z,acc1.z); acc1.w = fmaf(a1.w,w1.w,acc1.w);
        }
        float s = (acc0.x+acc0.y)+(acc0.z+acc0.w) + (acc1.x+acc1.y)+(acc1.z+acc1.w);
        if (n < H) q[b*H + n] = s + bq[n];
        else       gh[(size_t)b*4*H + (n-H)] = s;
      }
    }
    grid.sync();

    // ---- P2: scores + softmax, blocks 0..31 (b = bid) ----
    if (bid < B) {
      const int b = bid;
      const int lane = tid & 63, wave = tid >> 6;
      const float4* q4 = (const float4*)(q + b*H);
      const float4* v4 = (const float4*)Vw;
      for (int s = wave; s < S; s += 8) {
        const float4* k4 = (const float4*)(keys + ((size_t)b*S + s)*H);
        float acc = 0.f;
        #pragma unroll
        for (int j=0;j<4;j++){
          int i = lane + 64*j;
          float4 qv = q4[i], kv = k4[i], vv = v4[i];
          acc += fast_tanh(qv.x+kv.x)*vv.x;
          acc += fast_tanh(qv.y+kv.y)*vv.y;
          acc += fast_tanh(qv.z+kv.z)*vv.z;
          acc += fast_tanh(qv.w+kv.w)*vv.w;
        }
        #pragma unroll
        for (int off=32; off>0; off>>=1) acc += __shfl_down(acc, off);
        if (lane==0) sc_sh[s] = acc + bV[0];
      }
      __syncthreads();
      if (tid < 64) {
        float val = (tid < S) ? sc_sh[tid] : -1e30f;
        float m = val;
        #pragma unroll
        for (int off=32; off>0; off>>=1) m = fmaxf(m, __shfl_xor(m, off));
        float e = (tid < S) ? __expf(val - m) : 0.f;
        float ssum = e;
        #pragma unroll
        for (int off=32; off>0; off>>=1) ssum += __shfl_xor(ssum, off);
        if (tid < S) {
          float wv = e / ssum;
          w_glob[b*S + tid] = wv;
          attn_out[((size_t)b*T + t)*S + tid] = wv;
        }
      }
    }
    grid.sync();

    // ---- P3: gates = Gx[t] + gh + w·encW ; LSTM update. block=(b, m-chunk of 128) ----
    {
      const int b = bid >> 3, mc = bid & 7;
      if (tid < S) sc_sh[tid] = w_glob[b*S + tid];
      __syncthreads();
      {
        const int g = tid >> 7, mm = tid & 127;   // gate, m within chunk
        const int n = g*H + mc*128 + mm;
        const size_t gbase = (size_t)b*4*H;
        float a = Gx[(size_t)t*B*4*H + gbase + n] + gh[gbase + n];
        const float* ep = encW + (size_t)b*S*4*H + n;
        #pragma unroll 4
        for (int s = 0; s < S; ++s)
          a = fmaf(sc_sh[s], ep[(size_t)s*4*H], a);
        gacc[g][mm] = a;
      }
      __syncthreads();
      if (tid < 128) {
        const int m = mc*128 + tid;
        float ig = fast_sigmoid(gacc[0][tid]);
        float fg = fast_sigmoid(gacc[1][tid]);
        float gg = fast_tanh   (gacc[2][tid]);
        float og = fast_sigmoid(gacc[3][tid]);
        int idx = b*H + m;
        float c = fg * ccur[idx] + ig * gg;
        float hn = og * fast_tanh(c);
        ccur[idx] = c;
        hcur[idx] = hn;
        hhist[((size_t)b*T + t)*H + m] = hn;
      }
    }
    grid.sync();
  }
}

// ---------------- log_softmax in-place over rows of 16384 ----------------
__global__ __launch_bounds__(256) void k_logsm(float* __restrict__ p_all)
{
  float* p = p_all + (size_t)blockIdx.x * V;
  const int tid = threadIdx.x;
  const int lane = tid & 63, wave = tid >> 6;
  __shared__ float red[4];
  float4 v[16];
  float m = -1e30f;
  #pragma unroll
  for (int j=0;j<16;j++){
    v[j] = *(const float4*)(p + 4*(tid + 256*j));
    m = fmaxf(m, fmaxf(fmaxf(v[j].x, v[j].y), fmaxf(v[j].z, v[j].w)));
  }
  #pragma unroll
  for (int off=32; off>0; off>>=1) m = fmaxf(m, __shfl_xor(m, off));
  if (lane==0) red[wave] = m;
  __syncthreads();
  m = fmaxf(fmaxf(red[0], red[1]), fmaxf(red[2], red[3]));
  float ssum = 0.f;
  #pragma unroll
  for (int j=0;j<16;j++){
    ssum += __expf(v[j].x - m) + __expf(v[j].y - m) + __expf(v[j].z - m) + __expf(v[j].w - m);
  }
  #pragma unroll
  for (int off=32; off>0; off>>=1) ssum += __shfl_xor(ssum, off);
  __syncthreads();
  if (lane==0) red[wave] = ssum;
  __syncthreads();
  float lse = m + __logf(red[0] + red[1] + red[2] + red[3]);
  #pragma unroll
  for (int j=0;j<16;j++){
    float4 o; o.x = v[j].x - lse; o.y = v[j].y - lse; o.z = v[j].z - lse; o.w = v[j].w - lse;
    *(float4*)(p + 4*(tid + 256*j)) = o;
  }
}

// ---------------- final h/c copy ----------------
__global__ __launch_bounds__(256) void k_copyhc(const float* __restrict__ h, const float* __restrict__ c,
                                                float* __restrict__ oh, float* __restrict__ oc)
{
  int i = blockIdx.x*256 + threadIdx.x;
  oh[i] = h[i]; oc[i] = c[i];
}

extern "C" void kernel_launch(void* const* d_in, const int* in_sizes, int n_in,
                              void* d_out, int out_size, void* d_ws, size_t ws_size,
                              hipStream_t stream) {
  const float* enc   = (const float*)d_in[0];   // [B][S][H]
  const float* ehid  = (const float*)d_in[1];   // [1][B][H]
  const int*   tgt   = (const int*)  d_in[2];   // [B][T]
  const float* emb   = (const float*)d_in[3];   // [V][H]
  const float* Wq    = (const float*)d_in[4];
  const float* bq    = (const float*)d_in[5];
  const float* Wk    = (const float*)d_in[6];
  const float* bk    = (const float*)d_in[7];
  const float* Vw    = (const float*)d_in[8];
  const float* bV    = (const float*)d_in[9];
  const float* Wih   = (const float*)d_in[10];  // [4H][2H]
  const float* Whh   = (const float*)d_in[11];  // [4H][H]
  const float* bih   = (const float*)d_in[12];
  const float* bhh   = (const float*)d_in[13];
  const float* Wout  = (const float*)d_in[14];  // [V][H]
  const float* bout  = (const float*)d_in[15];

  float* out  = (float*)d_out;
  float* dec  = out;                          // [B][T][V] = 21.5M floats
  float* hf   = out + (size_t)B*T*V;
  float* cf   = hf + BH;
  float* attn = cf + BH;                      // [B][T][S]

  // encW and Gx live in dec's region (dead until logits GEMM overwrites it)
  float* encW = dec;                          // [B*S][4H] = 5.37M
  float* Gx   = dec + (size_t)B*S*4*H;        // [T*B][4H] = 5.37M

  float* ws = (float*)d_ws;
  size_t o = 0;
  float* keys  = ws + o; o += (size_t)B*S*H;    // 1.34M
  float* hhist = ws + o; o += (size_t)B*T*H;    // 1.34M (doubles as Xall)
  float* qbuf  = ws + o; o += BH;
  float* ghbuf = ws + o; o += (size_t)B*4*H;
  float* wglob = ws + o; o += B*S;
  float* hcur  = ws + o; o += BH;
  float* ccur  = ws + o; o += BH;
  float* bsum  = ws + o; o += 4*H;
  float* Xall  = hhist;                         // alias: Xall dead before hhist written

  k_init<<<BH/256, 256, 0, stream>>>(ehid, hcur, ccur);
  k_bsum<<<(4*H)/256, 256, 0, stream>>>(bih, bhh, bsum);
  k_gather<<<T*B, 256, 0, stream>>>(emb, tgt, Xall);

  // keys = enc @ Wk^T + bk           (M=1312, N=1024, K=1024)
  {
    dim3 grid((B*S + 127)/128, H/128);
    k_gemm<<<grid, 256, 0, stream>>>(enc, Wk, bk, keys, B*S, H, H, H, 0);
  }
  // Gx = Xall @ Wih[:, :H]^T + bsum  (M=1312, N=4096, K=1024)
  {
    dim3 grid((T*B + 127)/128, (4*H)/128);
    k_gemm<<<grid, 256, 0, stream>>>(Xall, Wih, bsum, Gx, T*B, 4*H, H, 2*H, 0);
  }
  // encW = enc @ Wih[:, H:]^T        (M=1312, N=4096, K=1024)
  {
    dim3 grid((B*S + 127)/128, (4*H)/128);
    k_gemm<<<grid, 256, 0, stream>>>(enc, Wih, nullptr, encW, B*S, 4*H, H, 2*H, H);
  }

  // the whole 41-step recurrence in one cooperative kernel
  {
    void* kargs[] = {
      (void*)&Wq, (void*)&bq, (void*)&Whh, (void*)&keys, (void*)&Vw, (void*)&bV,
      (void*)&Gx, (void*)&encW, (void*)&qbuf, (void*)&ghbuf, (void*)&wglob,
      (void*)&hcur, (void*)&ccur, (void*)&hhist, (void*)&attn
    };
    hipLaunchCooperativeKernel((const void*)k_loop, dim3(256), dim3(512), kargs, 0, stream);
  }

  // logits = hhist @ Wout^T + bout -> dec rows (row = b*T+t)
  {
    dim3 grid((B*T + 127)/128, V/128);
    k_gemm<<<grid, 256, 0, stream>>>(hhist, Wout, bout, dec, B*T, V, H, H, 0);
  }
  k_logsm<<<B*T, 256, 0, stream>>>(dec);
  k_copyhc<<<BH/256, 256, 0, stream>>>(hcur, ccur, hf, cf);
}

// Round 5
// 4518.872 us; speedup vs baseline: 2.4952x; 2.4952x over previous
//
#include <hip/hip_runtime.h>
#include <hip/hip_bf16.h>
#include <math.h>

#define B 32
#define S 41
#define T 41
#define H 1024
#define V 16384
#define BH (B*H)

typedef unsigned int uint;
typedef unsigned short ushort;
typedef __attribute__((ext_vector_type(8))) short bf16x8;
typedef __attribute__((ext_vector_type(4))) float f32x4;
typedef _Float16 h2v __attribute__((ext_vector_type(2)));

__device__ __forceinline__ float fast_sigmoid(float x){ return 1.f/(1.f + __expf(-x)); }
__device__ __forceinline__ float fast_tanh(float x){
  float e = __expf(-2.f*fabsf(x));
  float r = (1.f - e)/(1.f + e);
  return copysignf(r, x);
}
__device__ __forceinline__ ushort f2h(float f){ return __builtin_bit_cast(unsigned short, (_Float16)f); }
__device__ __forceinline__ float h2f(ushort u){ return (float)__builtin_bit_cast(_Float16, u); }
__device__ __forceinline__ h2v bc2(uint u){ return __builtin_bit_cast(h2v, u); }
__device__ __forceinline__ ushort f2bf(float f){
  uint u = __float_as_uint(f);
  u = u + 0x7FFFu + ((u>>16)&1u);
  return (ushort)(u>>16);
}

#if defined(__has_builtin)
#if __has_builtin(__builtin_amdgcn_fdot2)
#define HAS_FDOT2 1
#endif
#endif
__device__ __forceinline__ float dot2(h2v a, h2v b, float c){
#ifdef HAS_FDOT2
  return __builtin_amdgcn_fdot2(a, b, c, false);
#else
  return fmaf((float)a.x, (float)b.x, fmaf((float)a.y, (float)b.y, c));
#endif
}

// ---------------- gather teacher-forced embeddings (f32): Xall[t*B+b][:] = emb[tok] ----------------
__global__ __launch_bounds__(256) void k_gather(const float* __restrict__ emb,
    const int* __restrict__ tgt, float* __restrict__ Xall){
  int r = blockIdx.x;            // 0..T*B-1
  int t = r / B, b = r % B;
  int tok = (t==0) ? 0 : tgt[b*T + (t-1)];
  const float4* src = (const float4*)(emb + (size_t)tok*H);
  float4* dst = (float4*)(Xall + (size_t)r*H);
  dst[threadIdx.x] = src[threadIdx.x];
}

__global__ __launch_bounds__(256) void k_bsum(const float* __restrict__ a,
                                              const float* __restrict__ b, float* __restrict__ o){
  int i = blockIdx.x*256 + threadIdx.x;
  o[i] = a[i] + b[i];
}

// ---------------- f32 -> f16 row-major convert ----------------
__global__ __launch_bounds__(256) void k_cvt16(const float* __restrict__ src,
                                               ushort* __restrict__ dst, int n8){
  int i = blockIdx.x*256 + threadIdx.x;
  if (i >= n8) return;
  const float4* s4 = (const float4*)src + (size_t)i*2;
  float4 a = s4[0], b = s4[1];
  union { ushort us[8]; uint4 v; } p;
  p.us[0]=f2h(a.x); p.us[1]=f2h(a.y); p.us[2]=f2h(a.z); p.us[3]=f2h(a.w);
  p.us[4]=f2h(b.x); p.us[5]=f2h(b.y); p.us[6]=f2h(b.z); p.us[7]=f2h(b.w);
  ((uint4*)dst)[i] = p.v;
}

// ---------------- Wc16T[kb][n][8] = f16 of ([Wq;Whh])[n][kb*8..+7] ----------------
__global__ __launch_bounds__(256) void k_cvt_wc(const float* __restrict__ Wq,
    const float* __restrict__ Whh, ushort* __restrict__ Wc16T){
  const int kb = blockIdx.x;                   // 0..127
  const int n  = blockIdx.y*256 + threadIdx.x; // 0..5119
  const float* src = (n < H) ? (Wq + (size_t)n*H + kb*8)
                             : (Whh + (size_t)(n-H)*H + kb*8);
  float4 a = *(const float4*)src;
  float4 b = *(const float4*)(src+4);
  union { ushort us[8]; uint4 v; } p;
  p.us[0]=f2h(a.x); p.us[1]=f2h(a.y); p.us[2]=f2h(a.z); p.us[3]=f2h(a.w);
  p.us[4]=f2h(b.x); p.us[5]=f2h(b.y); p.us[6]=f2h(b.z); p.us[7]=f2h(b.w);
  ((uint4*)Wc16T)[kb*5120 + n] = p.v;
}

// ---------------- bf16 MFMA GEMM: C[m][n] = sum_k A[m][k]*W[n*wstride+woff+k] (+bias) ----------------
// f32 inputs converted to bf16 during staging. K=1024. 128x128 tile, BK=32, 256 thr, 4 waves 2x2.
__global__ __launch_bounds__(256) void k_bgemm(const float* __restrict__ A,
    const float* __restrict__ W, const float* __restrict__ bias, float* __restrict__ C,
    int M, int N, int wstride, int woff)
{
  __shared__ ushort As[128*40];   // row stride 40 ushorts (80B): 32 data + 8 pad
  __shared__ ushort Bs[128*40];
  const int tid = threadIdx.x;
  const int n0 = blockIdx.x*128, m0 = blockIdx.y*128;
  const int row = tid>>1, half = tid&1;
  const int lane = tid & 63, widx = tid >> 6;
  const int wm = (widx>>1)*64, wn = (widx&1)*64;

  int arow = m0 + row; if (arow > M-1) arow = M-1;
  const float* ga = A + (size_t)arow*1024 + half*16;
  const float* gw = W + (size_t)(n0+row)*wstride + woff + half*16;
  ushort* sa = &As[row*40 + half*16];
  ushort* sb = &Bs[row*40 + half*16];

  f32x4 acc[4][4] = {};

  for (int k0 = 0; k0 < 1024; k0 += 32) {
    float4 a0 = *(const float4*)(ga+k0),   a1 = *(const float4*)(ga+k0+4);
    float4 a2 = *(const float4*)(ga+k0+8), a3 = *(const float4*)(ga+k0+12);
    float4 w0 = *(const float4*)(gw+k0),   w1 = *(const float4*)(gw+k0+4);
    float4 w2 = *(const float4*)(gw+k0+8), w3 = *(const float4*)(gw+k0+12);
    __syncthreads();
    {
      union { ushort us[8]; uint4 v; } p, q;
      p.us[0]=f2bf(a0.x); p.us[1]=f2bf(a0.y); p.us[2]=f2bf(a0.z); p.us[3]=f2bf(a0.w);
      p.us[4]=f2bf(a1.x); p.us[5]=f2bf(a1.y); p.us[6]=f2bf(a1.z); p.us[7]=f2bf(a1.w);
      q.us[0]=f2bf(a2.x); q.us[1]=f2bf(a2.y); q.us[2]=f2bf(a2.z); q.us[3]=f2bf(a2.w);
      q.us[4]=f2bf(a3.x); q.us[5]=f2bf(a3.y); q.us[6]=f2bf(a3.z); q.us[7]=f2bf(a3.w);
      *(uint4*)sa = p.v; *(uint4*)(sa+8) = q.v;
      p.us[0]=f2bf(w0.x); p.us[1]=f2bf(w0.y); p.us[2]=f2bf(w0.z); p.us[3]=f2bf(w0.w);
      p.us[4]=f2bf(w1.x); p.us[5]=f2bf(w1.y); p.us[6]=f2bf(w1.z); p.us[7]=f2bf(w1.w);
      q.us[0]=f2bf(w2.x); q.us[1]=f2bf(w2.y); q.us[2]=f2bf(w2.z); q.us[3]=f2bf(w2.w);
      q.us[4]=f2bf(w3.x); q.us[5]=f2bf(w3.y); q.us[6]=f2bf(w3.z); q.us[7]=f2bf(w3.w);
      *(uint4*)sb = p.v; *(uint4*)(sb+8) = q.v;
    }
    __syncthreads();
    bf16x8 af[4], bf[4];
    #pragma unroll
    for (int i=0;i<4;i++)
      af[i] = *(const bf16x8*)&As[(wm + i*16 + (lane&15))*40 + (lane>>4)*8];
    #pragma unroll
    for (int j=0;j<4;j++)
      bf[j] = *(const bf16x8*)&Bs[(wn + j*16 + (lane&15))*40 + (lane>>4)*8];
    #pragma unroll
    for (int i=0;i<4;i++)
      #pragma unroll
      for (int j=0;j<4;j++)
        acc[i][j] = __builtin_amdgcn_mfma_f32_16x16x32_bf16(af[i], bf[j], acc[i][j], 0, 0, 0);
  }

  #pragma unroll
  for (int i=0;i<4;i++){
    #pragma unroll
    for (int j=0;j<4;j++){
      int n = n0 + wn + j*16 + (lane&15);
      float bv = bias ? bias[n] : 0.f;
      #pragma unroll
      for (int qq=0;qq<4;qq++){
        int m = m0 + wm + i*16 + ((lane>>4)<<2) + qq;
        if (m < M) C[(size_t)m*N + n] = acc[i][j][qq] + bv;
      }
    }
  }
}

// ---------------- the 41-step recurrence: 32 self-contained blocks (one per batch) ----------------
__global__ __launch_bounds__(1024) void k_loop(
    const ushort* __restrict__ Wc16T,   // [128][5120][8] f16
    const float* __restrict__ bq,
    const ushort* __restrict__ keys16,  // [B*S][1024] f16
    const float* __restrict__ Vw, const float* __restrict__ bV,
    const float* __restrict__ GxF,      // [T*B][4096] f32
    const ushort* __restrict__ encW16,  // [B*S][4096] f16
    const float* __restrict__ ehid,     // [B][H]
    float* __restrict__ hhist,          // [B*T][H] f32
    float* __restrict__ attn_out,       // [B][T][S]
    float* __restrict__ hf, float* __restrict__ cf)
{
  __shared__ __align__(16) ushort h16_sh[H];
  __shared__ __align__(16) float q_sh[H];
  __shared__ __align__(16) float vw_sh[H];
  __shared__ float sc_sh[64];

  const int b = blockIdx.x;
  const int tid = threadIdx.x;
  const int lane = tid & 63, wv = tid >> 6;

  h16_sh[tid] = f2h(ehid[b*H + tid]);
  if (tid < 256) *(float4*)&vw_sh[tid*4] = ((const float4*)Vw)[tid];
  const float bqr = bq[tid];
  const float bV0 = bV[0];
  float creg = 0.f;
  __syncthreads();

  const uint4* wc = (const uint4*)Wc16T;

  for (int t = 0; t < T; ++t) {
    // ---- P1: q[tid] and gh_{i,f,g,o}[tid] = dot(Wc rows, h) ----
    float qa = 0.f, g0 = 0.f, g1 = 0.f, g2 = 0.f, g3 = 0.f;
    {
      int idx = tid;
      #pragma unroll 2
      for (int kb = 0; kb < 128; ++kb) {
        uint4 hv = *(const uint4*)&h16_sh[kb*8];
        h2v h0 = bc2(hv.x), h1 = bc2(hv.y), h2_ = bc2(hv.z), h3 = bc2(hv.w);
        uint4 w0 = wc[idx];
        uint4 w1 = wc[idx + 1024];
        uint4 w2 = wc[idx + 2048];
        uint4 w3 = wc[idx + 3072];
        uint4 w4 = wc[idx + 4096];
        qa = dot2(bc2(w0.x),h0,qa); qa = dot2(bc2(w0.y),h1,qa); qa = dot2(bc2(w0.z),h2_,qa); qa = dot2(bc2(w0.w),h3,qa);
        g0 = dot2(bc2(w1.x),h0,g0); g0 = dot2(bc2(w1.y),h1,g0); g0 = dot2(bc2(w1.z),h2_,g0); g0 = dot2(bc2(w1.w),h3,g0);
        g1 = dot2(bc2(w2.x),h0,g1); g1 = dot2(bc2(w2.y),h1,g1); g1 = dot2(bc2(w2.z),h2_,g1); g1 = dot2(bc2(w2.w),h3,g1);
        g2 = dot2(bc2(w3.x),h0,g2); g2 = dot2(bc2(w3.y),h1,g2); g2 = dot2(bc2(w3.z),h2_,g2); g2 = dot2(bc2(w3.w),h3,g2);
        g3 = dot2(bc2(w4.x),h0,g3); g3 = dot2(bc2(w4.y),h1,g3); g3 = dot2(bc2(w4.z),h2_,g3); g3 = dot2(bc2(w4.w),h3,g3);
        idx += 5120;
      }
    }
    q_sh[tid] = qa + bqr;
    __syncthreads();

    // ---- P2: scores (16 waves over 41 s) ----
    for (int s = wv; s < S; s += 16) {
      const ushort* kr = keys16 + ((size_t)b*S + s)*H + lane*16;
      uint4 k0 = *(const uint4*)kr;
      uint4 k1 = *(const uint4*)(kr+8);
      const float* qp = q_sh + lane*16;
      const float* vp = vw_sh + lane*16;
      float part = 0.f;
      #define SC2(u, e) { h2v hh = bc2(u); \
        part += fast_tanh(qp[e] + (float)hh.x) * vp[e]; \
        part += fast_tanh(qp[e+1] + (float)hh.y) * vp[e+1]; }
      SC2(k0.x,0) SC2(k0.y,2) SC2(k0.z,4) SC2(k0.w,6)
      SC2(k1.x,8) SC2(k1.y,10) SC2(k1.z,12) SC2(k1.w,14)
      #undef SC2
      #pragma unroll
      for (int off=32; off>0; off>>=1) part += __shfl_xor(part, off);
      if (lane == 0) sc_sh[s] = part + bV0;
    }
    __syncthreads();

    // ---- P3: softmax over 41 (wave 0) ----
    if (tid < 64) {
      float val = (tid < S) ? sc_sh[tid] : -1e30f;
      float m = val;
      #pragma unroll
      for (int off=32; off>0; off>>=1) m = fmaxf(m, __shfl_xor(m, off));
      float e = (tid < S) ? __expf(val - m) : 0.f;
      float ssum = e;
      #pragma unroll
      for (int off=32; off>0; off>>=1) ssum += __shfl_xor(ssum, off);
      if (tid < S) {
        float w = e / ssum;
        sc_sh[tid] = w;
        attn_out[((size_t)b*T + t)*S + tid] = w;
      }
    }
    __syncthreads();

    // ---- P4: gates + LSTM (thread m = tid) ----
    {
      size_t gxb = ((size_t)t*B + b)*(4*H) + tid;
      float f0 = GxF[gxb]       + g0;
      float f1 = GxF[gxb + H]   + g1;
      float f2 = GxF[gxb + 2*H] + g2;
      float f3 = GxF[gxb + 3*H] + g3;
      const ushort* ep = encW16 + (size_t)b*S*(4*H) + tid;
      #pragma unroll 4
      for (int s = 0; s < S; ++s) {
        float w = sc_sh[s];
        const ushort* e4 = ep + (size_t)s*(4*H);
        f0 = fmaf(w, h2f(e4[0]),   f0);
        f1 = fmaf(w, h2f(e4[H]),   f1);
        f2 = fmaf(w, h2f(e4[2*H]), f2);
        f3 = fmaf(w, h2f(e4[3*H]), f3);
      }
      float ig = fast_sigmoid(f0);
      float fg = fast_sigmoid(f1);
      float gg = fast_tanh(f2);
      float og = fast_sigmoid(f3);
      creg = fg*creg + ig*gg;
      float hn = og * fast_tanh(creg);
      h16_sh[tid] = f2h(hn);
      hhist[((size_t)b*T + t)*H + tid] = hn;
      if (t == T-1) { hf[b*H + tid] = hn; cf[b*H + tid] = creg; }
    }
    __syncthreads();
  }
}

// ---------------- log_softmax in-place over rows of 16384 ----------------
__global__ __launch_bounds__(256) void k_logsm(float* __restrict__ p_all)
{
  float* p = p_all + (size_t)blockIdx.x * V;
  const int tid = threadIdx.x;
  const int lane = tid & 63, wave = tid >> 6;
  __shared__ float red[4];
  float4 v[16];
  float m = -1e30f;
  #pragma unroll
  for (int j=0;j<16;j++){
    v[j] = *(const float4*)(p + 4*(tid + 256*j));
    m = fmaxf(m, fmaxf(fmaxf(v[j].x, v[j].y), fmaxf(v[j].z, v[j].w)));
  }
  #pragma unroll
  for (int off=32; off>0; off>>=1) m = fmaxf(m, __shfl_xor(m, off));
  if (lane==0) red[wave] = m;
  __syncthreads();
  m = fmaxf(fmaxf(red[0], red[1]), fmaxf(red[2], red[3]));
  float ssum = 0.f;
  #pragma unroll
  for (int j=0;j<16;j++){
    ssum += __expf(v[j].x - m) + __expf(v[j].y - m) + __expf(v[j].z - m) + __expf(v[j].w - m);
  }
  #pragma unroll
  for (int off=32; off>0; off>>=1) ssum += __shfl_xor(ssum, off);
  __syncthreads();
  if (lane==0) red[wave] = ssum;
  __syncthreads();
  float lse = m + __logf(red[0] + red[1] + red[2] + red[3]);
  #pragma unroll
  for (int j=0;j<16;j++){
    float4 o; o.x = v[j].x - lse; o.y = v[j].y - lse; o.z = v[j].z - lse; o.w = v[j].w - lse;
    *(float4*)(p + 4*(tid + 256*j)) = o;
  }
}

extern "C" void kernel_launch(void* const* d_in, const int* in_sizes, int n_in,
                              void* d_out, int out_size, void* d_ws, size_t ws_size,
                              hipStream_t stream) {
  const float* enc   = (const float*)d_in[0];
  const float* ehid  = (const float*)d_in[1];
  const int*   tgt   = (const int*)  d_in[2];
  const float* emb   = (const float*)d_in[3];
  const float* Wq    = (const float*)d_in[4];
  const float* bq    = (const float*)d_in[5];
  const float* Wk    = (const float*)d_in[6];
  const float* bk    = (const float*)d_in[7];
  const float* Vw    = (const float*)d_in[8];
  const float* bV    = (const float*)d_in[9];
  const float* Wih   = (const float*)d_in[10];
  const float* Whh   = (const float*)d_in[11];
  const float* bih   = (const float*)d_in[12];
  const float* bhh   = (const float*)d_in[13];
  const float* Wout  = (const float*)d_in[14];
  const float* bout  = (const float*)d_in[15];

  float* out  = (float*)d_out;
  float* dec  = out;                          // [1312][16384] = 21,495,808 f32
  float* hf   = out + (size_t)B*T*V;
  float* cf   = hf + BH;
  float* attn = cf + BH;

  // scratch inside dec (all dead before the logits GEMM rewrites dec)
  float*  Xall   = dec;                       //  1,343,488 f32
  float*  keysF  = dec +  1343488;            //  1,343,488 f32
  float*  GxF    = dec +  2686976;            //  5,373,952 f32
  float*  encWF  = dec +  8060928;            //  5,373,952 f32
  ushort* keys16 = (ushort*)(dec + 13434880); //  1,343,488 f16 (671,744 slots)
  ushort* encW16 = (ushort*)(dec + 14106624); //  5,373,952 f16 (2,686,976 slots)
  ushort* Wc16T  = (ushort*)(dec + 16793600); //  5,242,880 f16 (2,621,440 slots) -> ends 19,415,040

  float* ws = (float*)d_ws;
  float* hhist = ws;                          // 1,343,488 f32
  float* bsum  = ws + 1343488;                // 4096

  k_gather<<<T*B, 256, 0, stream>>>(emb, tgt, Xall);
  k_bsum<<<(4*H)/256, 256, 0, stream>>>(bih, bhh, bsum);

  // keys = enc @ Wk^T + bk
  { dim3 g(H/128, 11);     k_bgemm<<<g, 256, 0, stream>>>(enc,  Wk,  bk,     keysF, B*S, H,   H,   0); }
  // Gx = Xall @ Wih[:, :H]^T + (bih+bhh)
  { dim3 g((4*H)/128, 11); k_bgemm<<<g, 256, 0, stream>>>(Xall, Wih, bsum,   GxF,   T*B, 4*H, 2*H, 0); }
  // encW = enc @ Wih[:, H:]^T
  { dim3 g((4*H)/128, 11); k_bgemm<<<g, 256, 0, stream>>>(enc,  Wih, nullptr,encWF, B*S, 4*H, 2*H, H); }

  k_cvt16<<<(B*S*H/8 + 255)/256, 256, 0, stream>>>(keysF, keys16, B*S*H/8);
  k_cvt16<<<(B*S*4*H/8 + 255)/256, 256, 0, stream>>>(encWF, encW16, B*S*4*H/8);
  { dim3 g(128, 20); k_cvt_wc<<<g, 256, 0, stream>>>(Wq, Whh, Wc16T); }

  // the 41-step recurrence: 32 independent blocks, no cross-block sync
  k_loop<<<B, 1024, 0, stream>>>(Wc16T, bq, keys16, Vw, bV, GxF, encW16, ehid,
                                 hhist, attn, hf, cf);

  // logits = hhist @ Wout^T + bout -> dec rows (row = b*T+t), then log_softmax
  { dim3 g(V/128, 11);     k_bgemm<<<g, 256, 0, stream>>>(hhist, Wout, bout, dec, B*T, V, H, 0); }
  k_logsm<<<B*T, 256, 0, stream>>>(dec);
}